// Round 10
// baseline (233.496 us; speedup 1.0000x reference)
//
#include <hip/hip_runtime.h>
#include <hip/hip_bf16.h>
#include <cstdint>

#define CIN   128
#define COUT  256
#define BATCH 16
#define HH    64
#define WW    64
#define TH    32
#define TW    32
#define NT    (BATCH*TH*TW)   /* 16384 winograd tiles */
#define APQ   (COUT*CIN)      /* U plane: 32768 elems */
#define BPQ   (NT*CIN)        /* V plane: 2097152 elems */

typedef __bf16 bf16x8 __attribute__((ext_vector_type(8)));
typedef float  f32x4  __attribute__((ext_vector_type(4)));

__device__ __forceinline__ void gload16(const void* g, void* l) {
    __builtin_amdgcn_global_load_lds(
        (const __attribute__((address_space(1))) uint32_t*)g,
        (__attribute__((address_space(3))) uint32_t*)l, 16, 0, 0);
}

// ---------------------------------------------------------------------------
// Kernel 1: weight transform  U[pq][k][c] = (G w G^T)[p][q], bf16
// ---------------------------------------------------------------------------
__global__ __launch_bounds__(256) void wg_wtrans(const float* __restrict__ w,
                                                 __hip_bfloat16* __restrict__ U) {
    int idx = blockIdx.x * 256 + threadIdx.x;       // idx = k*CIN + c
    if (idx >= COUT * CIN) return;
    const float* wp = w + idx * 9;
    float g[3][3];
#pragma unroll
    for (int x = 0; x < 3; x++)
#pragma unroll
        for (int y = 0; y < 3; y++) g[x][y] = wp[x * 3 + y];

    float t[4][3];
#pragma unroll
    for (int y = 0; y < 3; y++) {
        t[0][y] = g[0][y];
        t[1][y] = 0.5f * (g[0][y] + g[1][y] + g[2][y]);
        t[2][y] = 0.5f * (g[0][y] - g[1][y] + g[2][y]);
        t[3][y] = g[2][y];
    }
#pragma unroll
    for (int p = 0; p < 4; p++) {
        float u0 = t[p][0];
        float u1 = 0.5f * (t[p][0] + t[p][1] + t[p][2]);
        float u2 = 0.5f * (t[p][0] - t[p][1] + t[p][2]);
        float u3 = t[p][2];
        U[(p * 4 + 0) * APQ + idx] = __float2bfloat16(u0);
        U[(p * 4 + 1) * APQ + idx] = __float2bfloat16(u1);
        U[(p * 4 + 2) * APQ + idx] = __float2bfloat16(u2);
        U[(p * 4 + 3) * APQ + idx] = __float2bfloat16(u3);
    }
}

// ---------------------------------------------------------------------------
// Kernel 2: input transform  V[pq][bij][c] = (BT d BT^T)[p][q], bf16
// ---------------------------------------------------------------------------
__global__ __launch_bounds__(1024) void wg_itrans(const float* __restrict__ X,
                                                  __hip_bfloat16* __restrict__ V) {
    __shared__ float lds[32 * 265];
    const int c0 = blockIdx.x * 32;
    const int i  = blockIdx.y;
    const int b  = blockIdx.z;
    const int tid = threadIdx.x;

    for (int t = tid; t < 32 * 4; t += 1024) {
        int cc = t >> 2, r = t & 3;
        lds[cc * 265 + r * 66 + 0]  = 0.f;
        lds[cc * 265 + r * 66 + 65] = 0.f;
    }
    for (int t = tid; t < 32 * 4 * 64; t += 1024) {
        int x = t & 63, r = (t >> 6) & 3, cc = t >> 8;
        int y = 2 * i - 1 + r;
        float v = 0.f;
        if (y >= 0 && y < HH) v = X[(((b * CIN) + (c0 + cc)) * HH + y) * WW + x];
        lds[cc * 265 + r * 66 + 1 + x] = v;
    }
    __syncthreads();

    const int c = tid & 31;
    const int j = tid >> 5;
    const float* base = &lds[c * 265 + 2 * j];

    float t0[4], t1[4], t2[4], t3[4];
#pragma unroll
    for (int y = 0; y < 4; y++) {
        float a  = base[0 * 66 + y];
        float bb = base[1 * 66 + y];
        float cc = base[2 * 66 + y];
        float dd = base[3 * 66 + y];
        t0[y] = a - cc;
        t1[y] = bb + cc;
        t2[y] = cc - bb;
        t3[y] = bb - dd;
    }
    float vm[4][4];
#pragma unroll
    for (int p = 0; p < 4; p++) {
        const float* tp = (p == 0) ? t0 : (p == 1) ? t1 : (p == 2) ? t2 : t3;
        vm[p][0] = tp[0] - tp[2];
        vm[p][1] = tp[1] + tp[2];
        vm[p][2] = tp[2] - tp[1];
        vm[p][3] = tp[1] - tp[3];
    }

    const int bij = b * (TH * TW) + i * TW + j;
    const int vo  = bij * CIN + (c0 + c);
#pragma unroll
    for (int p = 0; p < 4; p++)
#pragma unroll
        for (int q = 0; q < 4; q++)
            V[(size_t)(p * 4 + q) * BPQ + vo] = __float2bfloat16(vm[p][q]);
}

// ---------------------------------------------------------------------------
// Kernel 3: fused GEMM + output transform — m97 geometry, 2 blocks/CU.
// Block [128 kout x 64 bij], 256 thr = 4 waves (2m x 2n), wave tile 64x32.
// BK=64, 32 iters (pq = t>>1, kb = (t&1)*64).
// A staged in LDS (4 bufs x 16KB = 64KB, depth 2, XOR-swizzled source:
// slot s = (4l+g)^(R&7) -> conflict-free ds_read_b128, optimal staging lines).
// B (V) loaded DIRECT global->reg, double-buffered named sets, 1 iter ahead.
// vmcnt ledger (B(t+1) then A(t+2) per iter): steady 12, tail 8 -> 0.
// One barrier/iter; lgkmcnt(4)/(0) splits kk0/kk1 MFMA groups.
// Per-pq fold into 4 register Y-planes (compile-time after full unroll).
// ---------------------------------------------------------------------------
#define ABUF 16384

__global__ __launch_bounds__(256, 2) void wg_gemm10(const __hip_bfloat16* __restrict__ U,
                                                    const __hip_bfloat16* __restrict__ V,
                                                    const float* __restrict__ bias,
                                                    float* __restrict__ out) {
    __shared__ char lds[4 * ABUF];       // 64 KB (A tiles only)

    // bijective XCD swizzle (512 % 8 == 0): 64 consecutive wg per XCD
    int orig = blockIdx.x;
    int wgid = (orig & 7) * 64 + (orig >> 3);
    const int mt = wgid & 1, nt = wgid >> 1;
    const int m0 = mt * 128, n0 = nt * 64;

    const int tid  = threadIdx.x;
    const int lane = tid & 63;
    const int wave = tid >> 6;
    const int wm = wave >> 1, wn = wave & 1;
    const int la = lane & 15, hq = lane >> 4;

    // ---- A staging (pre-swizzled source). chunk c: R=c>>3, s=c&7, g=s^(R&7)
    const __hip_bfloat16* paS[4];
    int ldsAoff[4];
#pragma unroll
    for (int ch = 0; ch < 4; ch++) {
        int c = ch * 256 + tid;          // 0..1023 (16KB / 16B)
        int R = c >> 3;
        int g = (c & 7) ^ (R & 7);
        paS[ch]   = U + (m0 + R) * CIN + g * 8;
        ldsAoff[ch] = c * 16;
    }
    // A ds_read offsets: row R, gran g=kk*4+hq -> byte R*128 + ((g^(R&7))<<4)
    const int aoff0 = (wm * 64 + la) * 128 + ((((0 * 4) + hq) ^ (la & 7)) << 4);
    const int aoff1 = (wm * 64 + la) * 128 + ((((1 * 4) + hq) ^ (la & 7)) << 4);

    // ---- B direct-load base: row n0+wn*32+la, k-part hq*8
    const __hip_bfloat16* pbS = V + (size_t)(n0 + wn * 32 + la) * CIN + hq * 8;

    f32x4 yac[2][2][4][2];
#pragma unroll
    for (int x = 0; x < 2; x++)
#pragma unroll
        for (int y = 0; y < 2; y++)
#pragma unroll
            for (int mi = 0; mi < 4; mi++)
#pragma unroll
                for (int nj = 0; nj < 2; nj++) yac[x][y][mi][nj] = (f32x4){0.f, 0.f, 0.f, 0.f};
    f32x4 mac[4][2];
    const f32x4 fz = (f32x4){0.f, 0.f, 0.f, 0.f};

    // named B sets: b<set><nj><kk>
    bf16x8 bX00, bX01, bX10, bX11, bY00, bY01, bY10, bY11;
    bf16x8 a00, a01, a02, a03, a10, a11, a12, a13;

    auto stageA = [&](int s) {
        char* sb = lds + (s & 3) * ABUF;
        const int pq = s >> 1, kb = (s & 1) * 64;
#pragma unroll
        for (int ch = 0; ch < 4; ch++)
            gload16(paS[ch] + (size_t)pq * APQ + kb, sb + ldsAoff[ch]);
    };

    auto fold = [&](int pq) {            // compile-time pq after unroll
        const int p = pq >> 2, q = pq & 3;
        const float s1p = (p >= 2) ? -1.f : 1.f;
        const float s1q = (q >= 2) ? -1.f : 1.f;
        if (p != 3 && q != 3) {
#pragma unroll
            for (int mi = 0; mi < 4; mi++)
#pragma unroll
                for (int nj = 0; nj < 2; nj++) yac[0][0][mi][nj] += mac[mi][nj];
        }
        if (p != 3 && q != 0) {
#pragma unroll
            for (int mi = 0; mi < 4; mi++)
#pragma unroll
                for (int nj = 0; nj < 2; nj++) yac[0][1][mi][nj] += s1q * mac[mi][nj];
        }
        if (p != 0 && q != 3) {
#pragma unroll
            for (int mi = 0; mi < 4; mi++)
#pragma unroll
                for (int nj = 0; nj < 2; nj++) yac[1][0][mi][nj] += s1p * mac[mi][nj];
        }
        if (p != 0 && q != 0) {
            const float s11 = s1p * s1q;
#pragma unroll
            for (int mi = 0; mi < 4; mi++)
#pragma unroll
                for (int nj = 0; nj < 2; nj++) yac[1][1][mi][nj] += s11 * mac[mi][nj];
        }
    };

// issue B(T) into set (P00..P11): [nj][kk]
#define IB(P00, P01, P10, P11, T)                                              \
    {                                                                          \
        const int pq_ = (T) >> 1, kb_ = ((T) & 1) * 64;                        \
        const __hip_bfloat16* bp_ = pbS + (size_t)pq_ * BPQ + kb_;             \
        P00 = *reinterpret_cast<const bf16x8*>(bp_);                           \
        P01 = *reinterpret_cast<const bf16x8*>(bp_ + 32);                      \
        P10 = *reinterpret_cast<const bf16x8*>(bp_ + 16 * CIN);                \
        P11 = *reinterpret_cast<const bf16x8*>(bp_ + 16 * CIN + 32);           \
    }

// one iteration with current B set (C**)  and next B set (N**)
#define ITER(T, C00, C01, C10, C11, N00, N01, N10, N11, INITF)                 \
    {                                                                          \
        if ((T) < 31) IB(N00, N01, N10, N11, (T) + 1)                          \
        __builtin_amdgcn_sched_barrier(0);                                     \
        if ((T) < 30) stageA((T) + 2);                                         \
        __builtin_amdgcn_sched_barrier(0);                                     \
        if ((T) >= 2 && ((T) & 1) == 0) fold(((T) >> 1) - 1);                  \
        if ((T) <= 29)      asm volatile("s_waitcnt vmcnt(12)");               \
        else if ((T) == 30) asm volatile("s_waitcnt vmcnt(8)");                \
        else                asm volatile("s_waitcnt vmcnt(0)");                \
        __builtin_amdgcn_s_barrier();                                          \
        __builtin_amdgcn_sched_barrier(0);                                     \
        {                                                                      \
            const char* rb_ = lds + ((T) & 3) * ABUF;                          \
            a00 = *reinterpret_cast<const bf16x8*>(rb_ + aoff0);               \
            a01 = *reinterpret_cast<const bf16x8*>(rb_ + aoff0 + 2048);        \
            a02 = *reinterpret_cast<const bf16x8*>(rb_ + aoff0 + 4096);        \
            a03 = *reinterpret_cast<const bf16x8*>(rb_ + aoff0 + 6144);        \
            a10 = *reinterpret_cast<const bf16x8*>(rb_ + aoff1);               \
            a11 = *reinterpret_cast<const bf16x8*>(rb_ + aoff1 + 2048);        \
            a12 = *reinterpret_cast<const bf16x8*>(rb_ + aoff1 + 4096);        \
            a13 = *reinterpret_cast<const bf16x8*>(rb_ + aoff1 + 6144);        \
        }                                                                      \
        __builtin_amdgcn_sched_barrier(0);                                     \
        asm volatile("s_waitcnt lgkmcnt(4)");                                  \
        __builtin_amdgcn_sched_barrier(0);                                     \
        __builtin_amdgcn_s_setprio(1);                                         \
        mac[0][0] = __builtin_amdgcn_mfma_f32_16x16x32_bf16(a00, C00, (INITF) ? fz : mac[0][0], 0, 0, 0); \
        mac[0][1] = __builtin_amdgcn_mfma_f32_16x16x32_bf16(a00, C10, (INITF) ? fz : mac[0][1], 0, 0, 0); \
        mac[1][0] = __builtin_amdgcn_mfma_f32_16x16x32_bf16(a01, C00, (INITF) ? fz : mac[1][0], 0, 0, 0); \
        mac[1][1] = __builtin_amdgcn_mfma_f32_16x16x32_bf16(a01, C10, (INITF) ? fz : mac[1][1], 0, 0, 0); \
        mac[2][0] = __builtin_amdgcn_mfma_f32_16x16x32_bf16(a02, C00, (INITF) ? fz : mac[2][0], 0, 0, 0); \
        mac[2][1] = __builtin_amdgcn_mfma_f32_16x16x32_bf16(a02, C10, (INITF) ? fz : mac[2][1], 0, 0, 0); \
        mac[3][0] = __builtin_amdgcn_mfma_f32_16x16x32_bf16(a03, C00, (INITF) ? fz : mac[3][0], 0, 0, 0); \
        mac[3][1] = __builtin_amdgcn_mfma_f32_16x16x32_bf16(a03, C10, (INITF) ? fz : mac[3][1], 0, 0, 0); \
        __builtin_amdgcn_s_setprio(0);                                         \
        __builtin_amdgcn_sched_barrier(0);                                     \
        asm volatile("s_waitcnt lgkmcnt(0)");                                  \
        __builtin_amdgcn_sched_barrier(0);                                     \
        __builtin_amdgcn_s_setprio(1);                                         \
        mac[0][0] = __builtin_amdgcn_mfma_f32_16x16x32_bf16(a10, C01, mac[0][0], 0, 0, 0); \
        mac[0][1] = __builtin_amdgcn_mfma_f32_16x16x32_bf16(a10, C11, mac[0][1], 0, 0, 0); \
        mac[1][0] = __builtin_amdgcn_mfma_f32_16x16x32_bf16(a11, C01, mac[1][0], 0, 0, 0); \
        mac[1][1] = __builtin_amdgcn_mfma_f32_16x16x32_bf16(a11, C11, mac[1][1], 0, 0, 0); \
        mac[2][0] = __builtin_amdgcn_mfma_f32_16x16x32_bf16(a12, C01, mac[2][0], 0, 0, 0); \
        mac[2][1] = __builtin_amdgcn_mfma_f32_16x16x32_bf16(a12, C11, mac[2][1], 0, 0, 0); \
        mac[3][0] = __builtin_amdgcn_mfma_f32_16x16x32_bf16(a13, C01, mac[3][0], 0, 0, 0); \
        mac[3][1] = __builtin_amdgcn_mfma_f32_16x16x32_bf16(a13, C11, mac[3][1], 0, 0, 0); \
        __builtin_amdgcn_s_setprio(0);                                         \
        __builtin_amdgcn_sched_barrier(0);                                     \
    }

    // prologue (issue order matters for the vmcnt ledger: A0, B0, A1)
    stageA(0);
    IB(bX00, bX01, bX10, bX11, 0)
    stageA(1);

#pragma unroll
    for (int tt = 0; tt < 32; tt += 2) {
        ITER(tt,     bX00, bX01, bX10, bX11, bY00, bY01, bY10, bY11, true)
        ITER(tt + 1, bY00, bY01, bY10, bY11, bX00, bX01, bX10, bX11, false)
    }
    fold(15);

#undef ITER
#undef IB

    // ---- writeout: D frag: col(bij)=lane&15, row(kout)=(lane>>4)*4+r ----
    const int lr = lane & 15, rg = lane >> 4;
#pragma unroll
    for (int mi = 0; mi < 4; mi++) {
#pragma unroll
        for (int r = 0; r < 4; r++) {
            const int kout = m0 + wm * 64 + mi * 16 + rg * 4 + r;
            const float bvv = bias[kout];
#pragma unroll
            for (int nj = 0; nj < 2; nj++) {
                const int bij = n0 + wn * 32 + nj * 16 + lr;
                const int bb = bij >> 10, ti = (bij >> 5) & 31, tj = bij & 31;
                float* op = out + (((size_t)bb * COUT + kout) * HH + 2 * ti) * WW + 2 * tj;
                *reinterpret_cast<float2*>(op) =
                    make_float2(yac[0][0][mi][nj][r] + bvv, yac[0][1][mi][nj][r] + bvv);
                *reinterpret_cast<float2*>(op + WW) =
                    make_float2(yac[1][0][mi][nj][r] + bvv, yac[1][1][mi][nj][r] + bvv);
            }
        }
    }
}

// ---------------------------------------------------------------------------
extern "C" void kernel_launch(void* const* d_in, const int* in_sizes, int n_in,
                              void* d_out, int out_size, void* d_ws, size_t ws_size,
                              hipStream_t stream) {
    const float* X    = (const float*)d_in[0];
    const float* w    = (const float*)d_in[1];
    const float* bias = (const float*)d_in[2];
    float* out        = (float*)d_out;

    __hip_bfloat16* U = (__hip_bfloat16*)d_ws;                       // 1 MB
    __hip_bfloat16* V = (__hip_bfloat16*)((char*)d_ws + (1u << 20)); // 64 MB

    wg_wtrans<<<(COUT * CIN + 255) / 256, 256, 0, stream>>>(w, U);
    wg_itrans<<<dim3(CIN / 32, TH, BATCH), 1024, 0, stream>>>(X, V);
    wg_gemm10<<<(COUT / 128) * (NT / 64), 256, 0, stream>>>(U, V, bias, out);
}